// Round 6
// baseline (248.326 us; speedup 1.0000x reference)
//
#include <hip/hip_runtime.h>

// TPLoss: pred [B,N] fp32, labels [B,N] int32 (0/1) -> scalar fp32
//   s = sigmoid(pred); TP = sum(s*l); SP = sum(s); SL = sum(l)
//   denom = 1 - N + SP + SL - 2*TP ;  loss = -mean_b(TP/denom)
//
// R5 result: nontemporal loads broke the 101us plateau -> ~73us (~3.7 TB/s
// read). The per-CU L1 fill cap was the R1-R4 bottleneck; nt bypasses it.
// R6 single-axis test: occupancy on the nt path. R5 ran 8 waves/CU (25%).
// Wave-per-HALF-row doubles the grid (2048 blocks = 8 blocks/CU) and
// smaller batches cut live VGPRs -> target ~20 waves/CU (2.5x). Row result
// combined across the half-row wave pair via LDS.

typedef float f4v __attribute__((ext_vector_type(4)));
typedef int   i4v __attribute__((ext_vector_type(4)));

#define BDIM 256
#define ROWS 4096
#define COLS 8192
#define HCHUNKS 16      // float4 chunks per lane per HALF-row (4096/64/4)
#define BATCH 8
#define NB (HCHUNKS / BATCH)   // 2 batches per wave

__global__ __launch_bounds__(BDIM, 5) void tploss_rows(
    const float* __restrict__ pred,
    const int* __restrict__ labels,
    float* __restrict__ row_out)
{
    const int tid  = threadIdx.x;
    const int lane = tid & 63;
    const int wave = tid >> 6;                 // 0..3
    const int row  = blockIdx.x * 2 + (wave >> 1);
    const int half = wave & 1;                 // which half of the row

    const size_t base = (size_t)row * COLS + (size_t)half * (COLS / 2);
    const f4v* pb = (const f4v*)(pred   + base) + lane;
    const i4v* lb = (const i4v*)(labels + base) + lane;

    float sp = 0.0f;   // sum sigmoid
    float tp = 0.0f;   // sum sigmoid*label
    int   sl = 0;      // sum label (exact)

    for (int b = 0; b < NB; ++b) {
        const f4v* ph = pb + b * BATCH * 64;
        const i4v* lh = lb + b * BATCH * 64;

        // ---- pred batch: 8 nt loads issued back-to-back ----
        f4v s[BATCH];
#pragma unroll
        for (int i = 0; i < BATCH; ++i) s[i] = __builtin_nontemporal_load(&ph[i * 64]);
#pragma unroll
        for (int i = 0; i < BATCH; ++i) asm volatile("" : "+v"(s[i]));  // pin batch

#pragma unroll
        for (int i = 0; i < BATCH; ++i) {
            f4v v = s[i];
            f4v r;
            // sigmoid via v_exp + v_rcp (~2^-21 rel err; rcp(inf)=0 correct limit)
            r.x = __builtin_amdgcn_rcpf(1.0f + __expf(-v.x));
            r.y = __builtin_amdgcn_rcpf(1.0f + __expf(-v.y));
            r.z = __builtin_amdgcn_rcpf(1.0f + __expf(-v.z));
            r.w = __builtin_amdgcn_rcpf(1.0f + __expf(-v.w));
            sp += (r.x + r.y) + (r.z + r.w);
            s[i] = r;  // hold sigmoids
        }

        // ---- label batches: 2 x 4 nt loads (lower live-VGPR peak) ----
#pragma unroll
        for (int c = 0; c < 2; ++c) {
            i4v q[4];
#pragma unroll
            for (int i = 0; i < 4; ++i) q[i] = __builtin_nontemporal_load(&lh[(c * 4 + i) * 64]);
#pragma unroll
            for (int i = 0; i < 4; ++i) asm volatile("" : "+v"(q[i]));

#pragma unroll
            for (int i = 0; i < 4; ++i) {
                f4v r = s[c * 4 + i];
                tp = fmaf(r.x, (float)q[i].x, tp);
                tp = fmaf(r.y, (float)q[i].y, tp);
                tp = fmaf(r.z, (float)q[i].z, tp);
                tp = fmaf(r.w, (float)q[i].w, tp);
                sl += (q[i].x + q[i].y) + (q[i].z + q[i].w);
            }
        }
    }

    float slf = (float)sl;

    // wave-64 butterfly
#pragma unroll
    for (int off = 32; off > 0; off >>= 1) {
        sp  += __shfl_down(sp,  off, 64);
        tp  += __shfl_down(tp,  off, 64);
        slf += __shfl_down(slf, off, 64);
    }

    // combine the two half-row waves of each row
    __shared__ float ssp[4], stp[4], ssl[4];
    if (lane == 0) { ssp[wave] = sp; stp[wave] = tp; ssl[wave] = slf; }
    __syncthreads();

    if (tid == 0) {
#pragma unroll
        for (int r = 0; r < 2; ++r) {
            float SP = ssp[2 * r] + ssp[2 * r + 1];
            float TP = stp[2 * r] + stp[2 * r + 1];
            float SL = ssl[2 * r] + ssl[2 * r + 1];
            float denom = 1.0f - (float)COLS + SP + SL - 2.0f * TP;
            row_out[blockIdx.x * 2 + r] = TP / denom;
        }
    }
}

__global__ __launch_bounds__(BDIM) void tploss_reduce(
    const float* __restrict__ row_out,
    float* __restrict__ out)
{
    const int tid = threadIdx.x;
    float s = 0.0f;
#pragma unroll
    for (int i = 0; i < ROWS / BDIM; ++i)
        s += row_out[i * BDIM + tid];

#pragma unroll
    for (int off = 32; off > 0; off >>= 1)
        s += __shfl_down(s, off, 64);

    __shared__ float sw[BDIM / 64];
    const int wave = tid >> 6;
    const int lane = tid & 63;
    if (lane == 0) sw[wave] = s;
    __syncthreads();

    if (tid == 0) {
        float tot = (sw[0] + sw[1]) + (sw[2] + sw[3]);
        out[0] = -tot * (1.0f / (float)ROWS);
    }
}

extern "C" void kernel_launch(void* const* d_in, const int* in_sizes, int n_in,
                              void* d_out, int out_size, void* d_ws, size_t ws_size,
                              hipStream_t stream) {
    const float* pred   = (const float*)d_in[0];
    const int*   labels = (const int*)d_in[1];
    float* row_out = (float*)d_ws;   // 4096 floats; fully overwritten each call

    tploss_rows<<<ROWS / 2, BDIM, 0, stream>>>(pred, labels, row_out);
    tploss_reduce<<<1, BDIM, 0, stream>>>(row_out, (float*)d_out);
}